// Round 14
// baseline (583.582 us; speedup 1.0000x reference)
//
#include <hip/hip_runtime.h>
#include <hip/hip_bf16.h>
#include <math.h>

#define HDIM 128
#define TPB 256

typedef __attribute__((ext_vector_type(8))) short bf16x8;
typedef __attribute__((ext_vector_type(4))) float f32x4;

static inline int ceil_div(int a, int b){ return (a + b - 1) / b; }

__device__ __forceinline__ float wave_sum(float v){
#pragma unroll
  for (int o = 32; o > 0; o >>= 1) v += __shfl_down(v, o, 64);
  return v;
}

__device__ __forceinline__ short f2bf(float f){
  __hip_bfloat16 h = __float2bfloat16(f);
  return *reinterpret_cast<short*>(&h);
}
__device__ __forceinline__ float bfb2f(short s){
  unsigned int u = ((unsigned int)(unsigned short)s) << 16;
  return __builtin_bit_cast(float, u);
}

// async global->LDS: 64 lanes x 16B; LDS dest is wave-uniform base (+lane*16 by HW)
__device__ __forceinline__ void gl_lds16(const short* g, short* l){
  __builtin_amdgcn_global_load_lds(
      (const __attribute__((address_space(1))) void*)g,
      (__attribute__((address_space(3))) void*)l, 16, 0, 0);
}

// ---------------------------------------------------------------------------
// CSR build for receivers. ef lives receiver-sorted.
// ---------------------------------------------------------------------------
__global__ void csr_hist(const int* __restrict__ rcv, int* __restrict__ deg, int E){
  int e = blockIdx.x * blockDim.x + threadIdx.x;
  if (e < E) atomicAdd(&deg[rcv[e]], 1);
}

__global__ void csr_scan(const int* __restrict__ deg, int* __restrict__ row_start,
                         int* __restrict__ cursor, int N, int E){
  __shared__ int part[1024];
  int t = threadIdx.x;
  int chunk = (N + 1023) / 1024;
  int lo = t * chunk, hi = min(lo + chunk, N);
  int s = 0;
  for (int i = lo; i < hi; i++) s += deg[i];
  part[t] = s;
  __syncthreads();
  for (int off = 1; off < 1024; off <<= 1){
    int v = (t >= off) ? part[t - off] : 0;
    __syncthreads();
    part[t] += v;
    __syncthreads();
  }
  int base = (t == 0) ? 0 : part[t - 1];
  for (int i = lo; i < hi; i++){
    row_start[i] = base;
    cursor[i]    = base;
    base += deg[i];
  }
  if (t == 1023) row_start[N] = E;
}

// ---------------------------------------------------------------------------
// Edge prep: permutation scatter + raw features (written permuted) + stats
// ---------------------------------------------------------------------------
__global__ void edge_prep(const float* __restrict__ pos,
                          const int* __restrict__ snd,
                          const int* __restrict__ rcv,
                          int* __restrict__ cursor,
                          int* __restrict__ psnd,
                          int* __restrict__ prcv,
                          float* __restrict__ ef_raw,
                          float* __restrict__ epart, int E){
  __shared__ float red[4][6];
  int tid = threadIdx.x, w = tid >> 6, l = tid & 63;
  int e = blockIdx.x * blockDim.x + tid;
  float s[6] = {0.f,0.f,0.f,0.f,0.f,0.f};
  if (e < E){
    int si = snd[e], ri = rcv[e];
    int p = atomicAdd(&cursor[ri], 1);
    psnd[p] = si;
    prcv[p] = ri;
    float rx = pos[2*si]   - pos[2*ri];
    float ry = pos[2*si+1] - pos[2*ri+1];
    float nm = sqrtf(rx*rx + ry*ry);
    ef_raw[3*p]   = rx;
    ef_raw[3*p+1] = ry;
    ef_raw[3*p+2] = nm;
    s[0] = rx; s[1] = ry; s[2] = nm;
    s[3] = rx*rx; s[4] = ry*ry; s[5] = nm*nm;
  }
#pragma unroll
  for (int k = 0; k < 6; k++) s[k] = wave_sum(s[k]);
  if (l == 0)
#pragma unroll
    for (int k = 0; k < 6; k++) red[w][k] = s[k];
  __syncthreads();
  if (tid < 6)
    epart[(size_t)blockIdx.x * 6 + tid] =
      red[0][tid] + red[1][tid] + red[2][tid] + red[3][tid];
}

// ---------------------------------------------------------------------------
// Node stats partials
// ---------------------------------------------------------------------------
__global__ void node_stats(const float* __restrict__ zl,
                           const float* __restrict__ z_target,
                           float* __restrict__ npart, int N){
  __shared__ float red[4][12];
  int tid = threadIdx.x, w = tid >> 6, l = tid & 63;
  int n = blockIdx.x * blockDim.x + tid;
  float s[12];
#pragma unroll
  for (int i = 0; i < 12; i++) s[i] = 0.f;
  if (n < N){
#pragma unroll
    for (int d = 0; d < 3; d++){
      float z = zl[3*n+d];
      float t = z_target[3*n+d] - z;
      s[d]   = z;  s[3+d] = z*z;
      s[6+d] = t;  s[9+d] = t*t;
    }
  }
#pragma unroll
  for (int i = 0; i < 12; i++) s[i] = wave_sum(s[i]);
  if (l == 0)
#pragma unroll
    for (int i = 0; i < 12; i++) red[w][i] = s[i];
  __syncthreads();
  if (tid < 12)
    npart[(size_t)blockIdx.x * 12 + tid] =
      red[0][tid] + red[1][tid] + red[2][tid] + red[3][tid];
}

// ---------------------------------------------------------------------------
// Reduce partials + finalize stats in one kernel.
// fin: em[0..2] es[3..5] nm[6..8] ns[9..11] om[12..14] os[15..17]
// ---------------------------------------------------------------------------
__global__ void reduce_finalize(const float* __restrict__ ep, int ne,
                                const float* __restrict__ np_, int nn,
                                float* __restrict__ fin, int E, int N){
  __shared__ float red[4];
  __shared__ float raw[18];
  int tid = threadIdx.x, w = tid >> 6, l = tid & 63;
  for (int j = 0; j < 6; j++){
    float s = 0.f;
    for (int b = tid; b < ne; b += 256) s += ep[(size_t)b * 6 + j];
    s = wave_sum(s);
    if (l == 0) red[w] = s;
    __syncthreads();
    if (tid == 0) raw[j] = red[0] + red[1] + red[2] + red[3];
    __syncthreads();
  }
  for (int j = 0; j < 12; j++){
    float s = 0.f;
    for (int b = tid; b < nn; b += 256) s += np_[(size_t)b * 12 + j];
    s = wave_sum(s);
    if (l == 0) red[w] = s;
    __syncthreads();
    if (tid == 0) raw[6 + j] = red[0] + red[1] + red[2] + red[3];
    __syncthreads();
  }
  if (tid == 0){
#pragma unroll
    for (int d = 0; d < 3; d++){
      float cE = (float)E, cN = (float)N;
      float m, v;
      m = raw[0+d] / cE; v = fmaxf(raw[3+d]/cE - m*m, 0.f);
      fin[0+d] = m;  fin[3+d]  = fmaxf(sqrtf(v), 1e-8f);
      m = raw[6+d] / cN; v = fmaxf(raw[9+d]/cN - m*m, 0.f);
      fin[6+d] = m;  fin[9+d]  = fmaxf(sqrtf(v), 1e-8f);
      m = raw[12+d] / cN; v = fmaxf(raw[15+d]/cN - m*m, 0.f);
      fin[12+d] = m; fin[15+d] = fmaxf(sqrtf(v), 1e-8f);
    }
  }
}

// ---------------------------------------------------------------------------
// Weight packing: fp32 [K][128] -> bf16 fragment-major (1KB per B-fragment)
// ---------------------------------------------------------------------------
__global__ void pack_weights(const float* __restrict__ encEW2,
                             const float* __restrict__ encNW2,
                             const float* __restrict__ decW1,
                             const float* __restrict__ beW1,
                             const float* __restrict__ beW2,
                             const float* __restrict__ bnW1,
                             const float* __restrict__ bnW2,
                             __hip_bfloat16* __restrict__ wp){
  int y = blockIdx.y;
  const float* src; __hip_bfloat16* dst; int K;
  if (y == 0){ src = encEW2; dst = wp;          K = 128; }
  else if (y == 1){ src = encNW2; dst = wp + 16384; K = 128; }
  else if (y == 2){ src = decW1;  dst = wp + 32768; K = 128; }
  else {
    int b = (y - 3) >> 2, j = (y - 3) & 3;
    __hip_bfloat16* base = wp + 49152 + b * 114688;
    if (j == 0){ src = beW1 + b*49152; dst = base;          K = 384; }
    else if (j == 1){ src = beW2 + b*16384; dst = base + 49152; K = 128; }
    else if (j == 2){ src = bnW1 + b*32768; dst = base + 65536; K = 256; }
    else { src = bnW2 + b*16384; dst = base + 98304; K = 128; }
  }
  int id = blockIdx.x * blockDim.x + threadIdx.x;
  if (id >= 128 * K) return;
  int c = id >> 12;
  int r = id & 4095;
  int t = r >> 9;
  int l = (r >> 3) & 63;
  int j = r & 7;
  int k = c * 32 + ((l >> 4) << 3) + j;
  int n = t * 16 + (l & 15);
  dst[id] = __float2bfloat16(src[k * 128 + n]);
}

// ---------------------------------------------------------------------------
// Fused encoder: out = (relu(norm(raw3)@W1+b1)) @ W2 + b2; W2 staged in LDS
// ---------------------------------------------------------------------------
__launch_bounds__(256)
__global__ void encoder_fused(const float* __restrict__ raw,
                              const float* __restrict__ mptr,
                              const float* __restrict__ sptr,
                              const float* __restrict__ W1,   // [3][128] f32
                              const float* __restrict__ b1,
                              const __hip_bfloat16* __restrict__ W2f, // frag-major
                              const float* __restrict__ b2,
                              __hip_bfloat16* __restrict__ out, int rows){
  __shared__ __align__(16) short bsh[16384];
  const int tid = threadIdx.x, w = tid >> 6, l = tid & 63, m = l & 15, q = l >> 4;
  const short* wsrc = (const short*)W2f;
#pragma unroll
  for (int i = 0; i < 8; i++){
    int inst = w * 8 + i;
    gl_lds16(wsrc + inst * 512 + l * 8, &bsh[inst * 512]);
  }
  float s0 = mptr[0], s1 = mptr[1], s2 = mptr[2];
  float d0 = sptr[0], d1 = sptr[1], d2 = sptr[2];
  const int row0 = blockIdx.x * 64 + w * 16;
  const int ra = min(row0 + m, rows - 1);
  float x0 = (raw[3*ra]   - s0) / d0;
  float x1 = (raw[3*ra+1] - s1) / d1;
  float x2 = (raw[3*ra+2] - s2) / d2;
  bf16x8 afr[4];
#pragma unroll
  for (int c = 0; c < 4; c++){
    int nb = c * 32 + q * 8;
#pragma unroll
    for (int j = 0; j < 8; j++){
      float h = b1[nb+j] + x0 * W1[nb+j] + x1 * W1[128+nb+j] + x2 * W1[256+nb+j];
      afr[c][j] = f2bf(fmaxf(h, 0.f));
    }
  }
  f32x4 acc[8];
#pragma unroll
  for (int t = 0; t < 8; t++) acc[t] = (f32x4){0.f,0.f,0.f,0.f};
  __syncthreads();
#pragma unroll
  for (int c = 0; c < 4; c++){
#pragma unroll
    for (int t = 0; t < 8; t++){
      bf16x8 b = *(const bf16x8*)&bsh[(c*8 + t)*512 + l*8];
      acc[t] = __builtin_amdgcn_mfma_f32_16x16x32_bf16(afr[c], b, acc[t], 0, 0, 0);
    }
  }
  const int row_d = row0 + q * 4;
#pragma unroll
  for (int t = 0; t < 8; t++){
    int col = t * 16 + m;
    float bb = b2[col];
#pragma unroll
    for (int r = 0; r < 4; r++){
      int e = row_d + r;
      if (e < rows) out[(size_t)e * HDIM + col] = __float2bfloat16(acc[t][r] + bb);
    }
  }
}

// ---------------------------------------------------------------------------
// Decoder layer 1: out_f32 = relu(A_bf16 @ W + b); W staged once in LDS
// ---------------------------------------------------------------------------
__launch_bounds__(256)
__global__ void gemm128_g(const __hip_bfloat16* __restrict__ A,
                          const __hip_bfloat16* __restrict__ Wf,
                          const float* __restrict__ bias,
                          float* __restrict__ out, int rows){
  __shared__ __align__(16) short bsh[16384];
  const int tid = threadIdx.x, w = tid >> 6, l = tid & 63, m = l & 15, q = l >> 4;
  const short* wsrc = (const short*)Wf;
#pragma unroll
  for (int i = 0; i < 8; i++){
    int inst = w * 8 + i;
    gl_lds16(wsrc + inst * 512 + l * 8, &bsh[inst * 512]);
  }
  const int row0 = blockIdx.x * 64 + w * 16;
  const int ra = min(row0 + m, rows - 1);
  const short* pa = (const short*)A + (size_t)ra * HDIM + q * 8;
  bf16x8 afr[4];
#pragma unroll
  for (int c = 0; c < 4; c++) afr[c] = *(const bf16x8*)(pa + c * 32);
  f32x4 acc[8];
#pragma unroll
  for (int t = 0; t < 8; t++) acc[t] = (f32x4){0.f,0.f,0.f,0.f};
  __syncthreads();
#pragma unroll
  for (int c = 0; c < 4; c++){
#pragma unroll
    for (int t = 0; t < 8; t++){
      bf16x8 b = *(const bf16x8*)&bsh[(c*8 + t)*512 + l*8];
      acc[t] = __builtin_amdgcn_mfma_f32_16x16x32_bf16(afr[c], b, acc[t], 0, 0, 0);
    }
  }
  const int row_d = row0 + q * 4;
#pragma unroll
  for (int t = 0; t < 8; t++){
    int col = t * 16 + m;
    float bb = bias[col];
#pragma unroll
    for (int r = 0; r < 4; r++){
      int e = row_d + r;
      if (e < rows) out[(size_t)e * HDIM + col] = fmaxf(acc[t][r] + bb, 0.f);
    }
  }
}

// ---------------------------------------------------------------------------
// msg_pre: u[n][0..255] = nf[n] @ [W1s | W1r]  (initial u, block 0 only)
// ---------------------------------------------------------------------------
__launch_bounds__(512)
__global__ void msg_pre(const __hip_bfloat16* __restrict__ nf,
                        const __hip_bfloat16* __restrict__ eWf, // full eW1 frag-major
                        __hip_bfloat16* __restrict__ u, int N){
  __shared__ __align__(16) short wsh[32768];   // 64 KB = chunks 4..11
  const int tid = threadIdx.x, w = tid >> 6, l = tid & 63, m = l & 15, q = l >> 4;
  const short* wsrc = (const short*)eWf + 4 * 4096;
#pragma unroll
  for (int i = 0; i < 8; i++){
    int inst = w * 8 + i;
    gl_lds16(wsrc + inst * 512 + l * 8, &wsh[inst * 512]);
  }
  const int row0 = blockIdx.x * 128 + w * 16;
  const int ra = min(row0 + m, N - 1);
  const short* pa = (const short*)nf + (size_t)ra * HDIM + q * 8;
  bf16x8 afr[4];
#pragma unroll
  for (int c = 0; c < 4; c++) afr[c] = *(const bf16x8*)(pa + c * 32);
  f32x4 acc[16];
#pragma unroll
  for (int t = 0; t < 16; t++) acc[t] = (f32x4){0.f,0.f,0.f,0.f};
  __syncthreads();
#pragma unroll
  for (int c = 0; c < 4; c++){
#pragma unroll
    for (int t = 0; t < 16; t++){
      int cc = (t < 8) ? c : (4 + c);
      bf16x8 b = *(const bf16x8*)&wsh[cc * 4096 + (t & 7) * 512 + l * 8];
      acc[t] = __builtin_amdgcn_mfma_f32_16x16x32_bf16(afr[c], b, acc[t], 0, 0, 0);
    }
  }
  const int row_d = row0 + q * 4;
#pragma unroll
  for (int t = 0; t < 16; t++){
    int col = t * 16 + m;
#pragma unroll
    for (int r = 0; r < 4; r++){
      int n = row_d + r;
      if (n < N) u[(size_t)n * 256 + col] = __float2bfloat16(acc[t][r]);
    }
  }
}

// ---------------------------------------------------------------------------
// Edge block (R13): ef += W2*relu(ef@W1e + u_s[s]+u_r[r]+b1)+b2
// ---------------------------------------------------------------------------
__launch_bounds__(512)
__global__ void edge_block(const int* __restrict__ psnd,
                           const int* __restrict__ prcv,
                           const __hip_bfloat16* __restrict__ u,   // [n][256] bf16
                           __hip_bfloat16* __restrict__ ef,
                           const __hip_bfloat16* __restrict__ Wfrag, // eW1|eW2 frag-major
                           const float* __restrict__ b1,
                           const float* __restrict__ b2,
                           int E){
  __shared__ __align__(16) short bsh[2][4096];
  __shared__ __align__(16) short hsh[8][16][136];
  const int tid = threadIdx.x, w = tid >> 6, l = tid & 63, m = l & 15, q = l >> 4;
  const short* wsrc = (const short*)Wfrag;
  gl_lds16(wsrc + w*512 + l*8, &bsh[0][w*512]);

  const int row0 = blockIdx.x * 128 + w * 16;
  const int ra = min(row0 + m, E - 1);
  const short* pe = (const short*)ef + (size_t)ra * HDIM + q * 8;
  bf16x8 afr[4];
#pragma unroll
  for (int c = 0; c < 4; c++) afr[c] = *(const bf16x8*)(pe + c * 32);

  {
    int grow = min(row0 + (l >> 2), E - 1);
    int us_row = psnd[grow], ur_row = prcv[grow];
    const short* pus = (const short*)u + (size_t)us_row * 256 + (l & 3) * 32;
    const short* pur = (const short*)u + (size_t)ur_row * 256 + 128 + (l & 3) * 32;
    short* hdst = &hsh[w][l >> 2][(l & 3) * 32];
#pragma unroll
    for (int k = 0; k < 4; k++){
      bf16x8 a = *(const bf16x8*)(pus + k * 8);
      bf16x8 b = *(const bf16x8*)(pur + k * 8);
      bf16x8 s;
#pragma unroll
      for (int j = 0; j < 8; j++) s[j] = f2bf(bfb2f(a[j]) + bfb2f(b[j]));
      *(bf16x8*)(hdst + k * 8) = s;
    }
  }
  const int orow = row0 + (l >> 2);
  const int orc = min(orow, E - 1);
  const short* pold = (const short*)ef + (size_t)orc * HDIM + (l & 3) * 32;
  bf16x8 vold[4];
#pragma unroll
  for (int k = 0; k < 4; k++) vold[k] = *(const bf16x8*)(pold + k * 8);

  f32x4 acc[8];
#pragma unroll
  for (int t = 0; t < 8; t++) acc[t] = (f32x4){0.f,0.f,0.f,0.f};
  __syncthreads();
#pragma unroll
  for (int c = 0; c < 4; c++){
    if (c + 1 < 4)
      gl_lds16(wsrc + (c+1)*4096 + w*512 + l*8, &bsh[(c+1)&1][w*512]);
    const short* bb = &bsh[c & 1][0];
#pragma unroll
    for (int t = 0; t < 8; t++){
      bf16x8 b = *(const bf16x8*)(bb + t*512 + l*8);
      acc[t] = __builtin_amdgcn_mfma_f32_16x16x32_bf16(afr[c], b, acc[t], 0, 0, 0);
    }
    if (c + 1 < 4) __syncthreads();
  }
#pragma unroll
  for (int t = 0; t < 8; t++){
    float bb = b1[t * 16 + m];
#pragma unroll
    for (int r = 0; r < 4; r++){
      float uval = bfb2f(hsh[w][q*4 + r][t*16 + m]);
      hsh[w][q*4 + r][t*16 + m] = f2bf(fmaxf(acc[t][r] + uval + bb, 0.f));
    }
  }
  const short* ph = &hsh[w][m][0] + q * 8;
  const short* w2 = wsrc + 49152;
  f32x4 acc2[8];
#pragma unroll
  for (int t = 0; t < 8; t++) acc2[t] = (f32x4){0.f,0.f,0.f,0.f};
#pragma unroll
  for (int c = 0; c < 4; c++){
    bf16x8 a = *(const bf16x8*)(ph + c * 32);
#pragma unroll
    for (int t = 0; t < 8; t++){
      bf16x8 b = *(const bf16x8*)(w2 + ((c*8 + t)*64 + l)*8);
      acc2[t] = __builtin_amdgcn_mfma_f32_16x16x32_bf16(a, b, acc2[t], 0, 0, 0);
    }
  }
#pragma unroll
  for (int t = 0; t < 8; t++){
    float bb = b2[t * 16 + m];
#pragma unroll
    for (int r = 0; r < 4; r++)
      hsh[w][q*4 + r][t*16 + m] = f2bf(acc2[t][r] + bb);
  }
  if (orow < E){
    const short* src = &hsh[w][l >> 2][(l & 3) * 32];
    short* dst = (short*)ef + (size_t)orow * HDIM + (l & 3) * 32;
#pragma unroll
    for (int k = 0; k < 4; k++){
      bf16x8 vnew = *(const bf16x8*)(src + k * 8);
      bf16x8 vo;
#pragma unroll
      for (int j = 0; j < 8; j++) vo[j] = f2bf(bfb2f(vnew[j]) + bfb2f(vold[k][j]));
      *(bf16x8*)(dst + k * 8) = vo;
    }
  }
}

// ---------------------------------------------------------------------------
// Node block (+fused u for next msg block): agg = CSR gather; nf += MLP([nf|agg]);
// if eWf_next: u[n] = nf_new @ [W1s|W1r]_next (B-frags from global, no barriers)
// ---------------------------------------------------------------------------
__launch_bounds__(512)
__global__ void node_block(const int* __restrict__ row_start,
                           const __hip_bfloat16* __restrict__ ef,  // permuted
                           __hip_bfloat16* __restrict__ nf,
                           const __hip_bfloat16* __restrict__ Wfrag, // nW1|nW2
                           const float* __restrict__ b1,
                           const float* __restrict__ b2,
                           const __hip_bfloat16* __restrict__ eWf_next, // or null
                           __hip_bfloat16* __restrict__ u,
                           int N){
  __shared__ __align__(16) short bsh[2][4096];
  __shared__ __align__(16) short hsh[8][16][136];
  const int tid = threadIdx.x, w = tid >> 6, l = tid & 63, m = l & 15, q = l >> 4;
  const short* wsrc = (const short*)Wfrag;
  gl_lds16(wsrc + w*512 + l*8, &bsh[0][w*512]);

  const int row0 = blockIdx.x * 128 + w * 16;
  const int ra = min(row0 + m, N - 1);
  const short* pn = (const short*)nf + (size_t)ra * HDIM + q * 8;
  bf16x8 afr[8];
#pragma unroll
  for (int c = 0; c < 4; c++) afr[c] = *(const bf16x8*)(pn + c * 32);
  const int orow = row0 + (l >> 2);
  const int orc = min(orow, N - 1);
  const short* pold = (const short*)nf + (size_t)orc * HDIM + (l & 3) * 32;
  bf16x8 vold[4];
#pragma unroll
  for (int k = 0; k < 4; k++) vold[k] = *(const bf16x8*)(pold + k * 8);

  float sum[4][8];
#pragma unroll
  for (int c = 0; c < 4; c++)
#pragma unroll
    for (int j = 0; j < 8; j++) sum[c][j] = 0.f;
  int s0 = row_start[ra], s1 = row_start[ra + 1];
  for (int it = s0; it < s1; it++){
    const short* pf = (const short*)ef + (size_t)it * HDIM + q * 8;
#pragma unroll
    for (int c = 0; c < 4; c++){
      bf16x8 v = *(const bf16x8*)(pf + c * 32);
#pragma unroll
      for (int j = 0; j < 8; j++) sum[c][j] += bfb2f(v[j]);
    }
  }
#pragma unroll
  for (int c = 0; c < 4; c++)
#pragma unroll
    for (int j = 0; j < 8; j++) afr[4 + c][j] = f2bf(sum[c][j]);

  f32x4 acc[8];
#pragma unroll
  for (int t = 0; t < 8; t++) acc[t] = (f32x4){0.f,0.f,0.f,0.f};
  __syncthreads();
#pragma unroll
  for (int c = 0; c < 8; c++){
    if (c + 1 < 8)
      gl_lds16(wsrc + (c+1)*4096 + w*512 + l*8, &bsh[(c+1)&1][w*512]);
    const short* bb = &bsh[c & 1][0];
#pragma unroll
    for (int t = 0; t < 8; t++){
      bf16x8 b = *(const bf16x8*)(bb + t*512 + l*8);
      acc[t] = __builtin_amdgcn_mfma_f32_16x16x32_bf16(afr[c], b, acc[t], 0, 0, 0);
    }
    if (c + 1 < 8) __syncthreads();
  }
#pragma unroll
  for (int t = 0; t < 8; t++){
    float bb = b1[t * 16 + m];
#pragma unroll
    for (int r = 0; r < 4; r++)
      hsh[w][q*4 + r][t*16 + m] = f2bf(fmaxf(acc[t][r] + bb, 0.f));
  }
  const short* ph = &hsh[w][m][0] + q * 8;
  const short* w2 = wsrc + 32768;
  f32x4 acc2[8];
#pragma unroll
  for (int t = 0; t < 8; t++) acc2[t] = (f32x4){0.f,0.f,0.f,0.f};
#pragma unroll
  for (int c = 0; c < 4; c++){
    bf16x8 a = *(const bf16x8*)(ph + c * 32);
#pragma unroll
    for (int t = 0; t < 8; t++){
      bf16x8 b = *(const bf16x8*)(w2 + ((c*8 + t)*64 + l)*8);
      acc2[t] = __builtin_amdgcn_mfma_f32_16x16x32_bf16(a, b, acc2[t], 0, 0, 0);
    }
  }
#pragma unroll
  for (int t = 0; t < 8; t++){
    float bb = b2[t * 16 + m];
#pragma unroll
    for (int r = 0; r < 4; r++)
      hsh[w][q*4 + r][t*16 + m] = f2bf(acc2[t][r] + bb);
  }
  // residual add; store nf_new to global AND back into hsh (wave-private)
  {
    short* srcm = &hsh[w][l >> 2][(l & 3) * 32];
    short* dst = (short*)nf + (size_t)orow * HDIM + (l & 3) * 32;
#pragma unroll
    for (int k = 0; k < 4; k++){
      bf16x8 vnew = *(const bf16x8*)(srcm + k * 8);
      bf16x8 vo;
#pragma unroll
      for (int j = 0; j < 8; j++) vo[j] = f2bf(bfb2f(vnew[j]) + bfb2f(vold[k][j]));
      if (orow < N) *(bf16x8*)(dst + k * 8) = vo;
      *(bf16x8*)(srcm + k * 8) = vo;
    }
  }
  // fused u for next message block: u = nf_new @ [W1s|W1r]_next
  if (eWf_next){
    const short* wn = (const short*)eWf_next;
    bf16x8 afr2[4];
#pragma unroll
    for (int c = 0; c < 4; c++) afr2[c] = *(const bf16x8*)(ph + c * 32);
    const int row_d = row0 + q * 4;
#pragma unroll
    for (int t = 0; t < 16; t++){
      f32x4 a3 = (f32x4){0.f,0.f,0.f,0.f};
      const short* wbase = wn + ((t < 8) ? (4 + 0) : (8 + 0)) * 4096 + (t & 7) * 512 + l * 8;
#pragma unroll
      for (int c = 0; c < 4; c++){
        bf16x8 b = *(const bf16x8*)(wbase + c * 4096);
        a3 = __builtin_amdgcn_mfma_f32_16x16x32_bf16(afr2[c], b, a3, 0, 0, 0);
      }
      int col = t * 16 + m;
#pragma unroll
      for (int r = 0; r < 4; r++){
        int n = row_d + r;
        if (n < N) u[(size_t)n * 256 + col] = __float2bfloat16(a3[r]);
      }
    }
  }
}

// ---------------------------------------------------------------------------
// Decoder final layer: [rows,128] fp32 @ [128,3] + b
// ---------------------------------------------------------------------------
__global__ void dec_final(const float* __restrict__ hbuf,
                          const float* __restrict__ W2,
                          const float* __restrict__ b2,
                          float* __restrict__ outd, int rows){
  __shared__ float hl[64 * 129];
  __shared__ float Wl[HDIM * 3];
  __shared__ float bl[3];
  int t = threadIdx.x;
  int node0 = blockIdx.x * 64;
  for (int i = t; i < HDIM * 3; i += 256) Wl[i] = W2[i];
  if (t < 3) bl[t] = b2[t];
#pragma unroll
  for (int i = 0; i < 32; i++){
    int lin = t + i * 256;
    int r = lin >> 7;
    int c = lin & 127;
    int node = node0 + r;
    hl[r * 129 + c] = (node < rows) ? hbuf[(size_t)node * HDIM + c] : 0.f;
  }
  __syncthreads();
  if (t < 64){
    int node = node0 + t;
    if (node < rows){
      float a0 = bl[0], a1 = bl[1], a2 = bl[2];
      for (int k = 0; k < HDIM; k++){
        float v = hl[t * 129 + k];
        a0 += v * Wl[k * 3];
        a1 += v * Wl[k * 3 + 1];
        a2 += v * Wl[k * 3 + 2];
      }
      outd[3 * node]     = a0;
      outd[3 * node + 1] = a1;
      outd[3 * node + 2] = a2;
    }
  }
}

// ---------------------------------------------------------------------------
// Epilogue + finalize (partials, no atomics)
// ---------------------------------------------------------------------------
__global__ void epilogue(const float* __restrict__ dec_out,
                         const float* __restrict__ zl,
                         const float* __restrict__ z_target,
                         const float* __restrict__ fin,
                         float* __restrict__ d_out,
                         float* __restrict__ lpart, int N){
  __shared__ float red[4][4];
  int tid = threadIdx.x, w = tid >> 6, l = tid & 63;
  int n = blockIdx.x * blockDim.x + tid;
  float s[4] = {0.f,0.f,0.f,0.f};
  if (n < N){
#pragma unroll
    for (int d = 0; d < 3; d++){
      float om = fin[12 + d], os = fin[15 + d];
      float o   = dec_out[3*n + d];
      float zld = zl[3*n + d];
      float zt  = z_target[3*n + d];
      float tgt = zt - zld;
      float tn  = (tgt - om) / os;
      float diff = tn - o;
      s[0] += diff * diff;
      float zp = zld + o * os + om;
      d_out[3*n + d] = zp;
      float e = zp - zt;
      s[1 + d] = e * e;
    }
  }
#pragma unroll
  for (int k = 0; k < 4; k++) s[k] = wave_sum(s[k]);
  if (l == 0)
#pragma unroll
    for (int k = 0; k < 4; k++) red[w][k] = s[k];
  __syncthreads();
  if (tid < 4)
    lpart[(size_t)blockIdx.x * 4 + tid] =
      red[0][tid] + red[1][tid] + red[2][tid] + red[3][tid];
}

__global__ void finalize_out(const float* __restrict__ lpart, int nb,
                             float* __restrict__ d_out, int N){
  __shared__ float red[4];
  __shared__ float vals[4];
  int tid = threadIdx.x, w = tid >> 6, l = tid & 63;
  for (int j = 0; j < 4; j++){
    float s = 0.f;
    for (int b = tid; b < nb; b += 256) s += lpart[(size_t)b * 4 + j];
    s = wave_sum(s);
    if (l == 0) red[w] = s;
    __syncthreads();
    if (tid == 0) vals[j] = red[0] + red[1] + red[2] + red[3];
    __syncthreads();
  }
  if (tid == 0){
    float cN = (float)N;
    float loss = vals[0] / (3.f * cN);
    float rmse = (sqrtf(vals[1] / cN) + sqrtf(vals[2] / cN) + sqrtf(vals[3] / cN)) / 3.f;
    d_out[(size_t)3 * N]     = loss;
    d_out[(size_t)3 * N + 1] = rmse;
  }
}

// ---------------------------------------------------------------------------
extern "C" void kernel_launch(void* const* d_in, const int* in_sizes, int n_in,
                              void* d_out, int out_size, void* d_ws, size_t ws_size,
                              hipStream_t stream){
  const float* z           = (const float*)d_in[0];
  const float* z_target    = (const float*)d_in[1];
  const float* pos         = (const float*)d_in[2];
  const float* enc_node_W1 = (const float*)d_in[3];
  const float* enc_node_b1 = (const float*)d_in[4];
  const float* enc_node_W2 = (const float*)d_in[5];
  const float* enc_node_b2 = (const float*)d_in[6];
  const float* enc_edge_W1 = (const float*)d_in[7];
  const float* enc_edge_b1 = (const float*)d_in[8];
  const float* enc_edge_W2 = (const float*)d_in[9];
  const float* enc_edge_b2 = (const float*)d_in[10];
  const float* dec_W1      = (const float*)d_in[11];
  const float* dec_b1      = (const float*)d_in[12];
  const float* dec_W2      = (const float*)d_in[13];
  const float* dec_b2      = (const float*)d_in[14];
  const float* blk_edge_W1 = (const float*)d_in[15];
  const float* blk_edge_b1 = (const float*)d_in[16];
  const float* blk_edge_W2 = (const float*)d_in[17];
  const float* blk_edge_b2 = (const float*)d_in[18];
  const float* blk_node_W1 = (const float*)d_in[19];
  const float* blk_node_b1 = (const float*)d_in[20];
  const float* blk_node_W2 = (const float*)d_in[21];
  const float* blk_node_b2 = (const float*)d_in[22];
  const int*   senders     = (const int*)d_in[23];
  const int*   receivers   = (const int*)d_in[24];

  const int N = in_sizes[1] / 3;
  const int E = in_sizes[23];
  const float* zl = z + (size_t)N * 3;

  const int neb = ceil_div(E, TPB);
  const int nnb = ceil_div(N, TPB);

  char* p = (char*)d_ws;
  auto carve = [&](size_t bytes) -> char* {
    char* r = p; p += (bytes + 255) & ~(size_t)255; return r;
  };
  float* stats_fin = (float*)carve(32 * 4);
  float* epart     = (float*)carve((size_t)neb * 6 * 4);
  float* npart     = (float*)carve((size_t)nnb * 12 * 4);
  float* lpart     = (float*)carve((size_t)nnb * 4 * 4);
  float* ef_raw    = (float*)carve((size_t)E * 3 * 4);
  float* dec_out   = (float*)carve((size_t)N * 3 * 4);
  float* hbuf      = (float*)carve((size_t)N * HDIM * 4);
  int*   deg       = (int*)carve((size_t)N * 4);
  int*   row_start = (int*)carve((size_t)(N + 1) * 4);
  int*   cursor    = (int*)carve((size_t)N * 4);
  int*   psnd      = (int*)carve((size_t)E * 4);
  int*   prcv      = (int*)carve((size_t)E * 4);
  __hip_bfloat16* wp = (__hip_bfloat16*)carve((size_t)507904 * 2);
  __hip_bfloat16* ef = (__hip_bfloat16*)carve((size_t)E * HDIM * 2);
  __hip_bfloat16* nf = (__hip_bfloat16*)carve((size_t)N * HDIM * 2);
  __hip_bfloat16* u  = (__hip_bfloat16*)carve((size_t)N * 256 * 2);

  float* out = (float*)d_out;

  hipMemsetAsync(deg, 0, (size_t)N * 4, stream);

  csr_hist<<<neb, TPB, 0, stream>>>(receivers, deg, E);
  csr_scan<<<1, 1024, 0, stream>>>(deg, row_start, cursor, N, E);
  edge_prep<<<neb, TPB, 0, stream>>>(pos, senders, receivers, cursor,
                                     psnd, prcv, ef_raw, epart, E);

  node_stats<<<nnb, TPB, 0, stream>>>(zl, z_target, npart, N);
  reduce_finalize<<<1, TPB, 0, stream>>>(epart, neb, npart, nnb, stats_fin, E, N);

  pack_weights<<<dim3(192, 19), TPB, 0, stream>>>(enc_edge_W2, enc_node_W2, dec_W1,
                                                  blk_edge_W1, blk_edge_W2,
                                                  blk_node_W1, blk_node_W2, wp);

  encoder_fused<<<ceil_div(E, 64), TPB, 0, stream>>>(ef_raw, stats_fin + 0, stats_fin + 3,
                                                     enc_edge_W1, enc_edge_b1,
                                                     wp, enc_edge_b2, ef, E);
  encoder_fused<<<ceil_div(N, 64), TPB, 0, stream>>>(zl, stats_fin + 6, stats_fin + 9,
                                                     enc_node_W1, enc_node_b1,
                                                     wp + 16384, enc_node_b2, nf, N);

  // initial u (for message block 0)
  msg_pre<<<ceil_div(N, 128), 512, 0, stream>>>(nf, wp + 49152, u, N);

  for (int b = 0; b < 4; b++){
    const __hip_bfloat16* eWf = wp + 49152 + (size_t)b * 114688;   // eW1|eW2
    const __hip_bfloat16* nWf = eWf + 65536;                       // nW1|nW2
    const __hip_bfloat16* eWf_next = (b < 3) ? (eWf + 114688) : nullptr;
    const float* eb1 = blk_edge_b1 + (size_t)b * 128;
    const float* eb2 = blk_edge_b2 + (size_t)b * 128;
    const float* nb1 = blk_node_b1 + (size_t)b * 128;
    const float* nb2 = blk_node_b2 + (size_t)b * 128;

    edge_block<<<ceil_div(E, 128), 512, 0, stream>>>(psnd, prcv, u, ef,
                                                     eWf, eb1, eb2, E);
    node_block<<<ceil_div(N, 128), 512, 0, stream>>>(row_start, ef, nf,
                                                     nWf, nb1, nb2,
                                                     eWf_next, u, N);
  }

  gemm128_g<<<ceil_div(N, 64), TPB, 0, stream>>>(nf, wp + 32768, dec_b1, hbuf, N);
  dec_final<<<ceil_div(N, 64), TPB, 0, stream>>>(hbuf, dec_W2, dec_b2, dec_out, N);

  epilogue<<<nnb, TPB, 0, stream>>>(dec_out, zl, z_target, stats_fin,
                                    out, lpart, N);
  finalize_out<<<1, TPB, 0, stream>>>(lpart, nnb, out, N);
}

// Round 15
// 524.984 us; speedup vs baseline: 1.1116x; 1.1116x over previous
//
#include <hip/hip_runtime.h>
#include <hip/hip_bf16.h>
#include <math.h>

#define HDIM 128
#define TPB 256

typedef __attribute__((ext_vector_type(8))) short bf16x8;
typedef __attribute__((ext_vector_type(4))) float f32x4;

static inline int ceil_div(int a, int b){ return (a + b - 1) / b; }

__device__ __forceinline__ float wave_sum(float v){
#pragma unroll
  for (int o = 32; o > 0; o >>= 1) v += __shfl_down(v, o, 64);
  return v;
}
__device__ __forceinline__ int wave_sum_i(int v){
#pragma unroll
  for (int o = 32; o > 0; o >>= 1) v += __shfl_down(v, o, 64);
  return v;
}

__device__ __forceinline__ short f2bf(float f){
  __hip_bfloat16 h = __float2bfloat16(f);
  return *reinterpret_cast<short*>(&h);
}
__device__ __forceinline__ float bfb2f(short s){
  unsigned int u = ((unsigned int)(unsigned short)s) << 16;
  return __builtin_bit_cast(float, u);
}

// async global->LDS: 64 lanes x 16B; LDS dest is wave-uniform base (+lane*16 by HW)
__device__ __forceinline__ void gl_lds16(const short* g, short* l){
  __builtin_amdgcn_global_load_lds(
      (const __attribute__((address_space(1))) void*)g,
      (__attribute__((address_space(3))) void*)l, 16, 0, 0);
}

// ---------------------------------------------------------------------------
// CSR build for receivers. ef lives receiver-sorted.
// Parallel 3-phase scan (replaces the 40-60us single-block serial scan).
// ---------------------------------------------------------------------------
__global__ void csr_hist(const int* __restrict__ rcv, int* __restrict__ deg, int E){
  int e = blockIdx.x * blockDim.x + threadIdx.x;
  if (e < E) atomicAdd(&deg[rcv[e]], 1);
}

// pass1: per-1024-block sums of deg
__global__ void scan_pass1(const int* __restrict__ deg, int* __restrict__ bsum, int N){
  __shared__ int red[4];
  int tid = threadIdx.x;
  int base = blockIdx.x * 1024;
  int s = 0;
  for (int i = tid; i < 1024; i += 256){
    int idx = base + i;
    if (idx < N) s += deg[idx];
  }
  s = wave_sum_i(s);
  if ((tid & 63) == 0) red[tid >> 6] = s;
  __syncthreads();
  if (tid == 0) bsum[blockIdx.x] = red[0] + red[1] + red[2] + red[3];
}

// pass2: serial exclusive scan over ~30 block sums (trivial)
__global__ void scan_pass2(const int* __restrict__ bsum, int* __restrict__ boff,
                           int nb, int* __restrict__ row_start, int N, int E){
  if (threadIdx.x == 0){
    int acc = 0;
    for (int b = 0; b < nb; b++){ boff[b] = acc; acc += bsum[b]; }
    row_start[N] = E;
  }
}

// pass3: local exclusive scan within each 1024 block; write row_start+cursor
__global__ void scan_pass3(const int* __restrict__ deg, const int* __restrict__ boff,
                           int* __restrict__ row_start, int* __restrict__ cursor, int N){
  __shared__ int tsum[256];
  int tid = threadIdx.x;
  int base = blockIdx.x * 1024;
  int i0 = base + tid * 4;
  int v[4];
  int s = 0;
#pragma unroll
  for (int k = 0; k < 4; k++){
    int idx = i0 + k;
    v[k] = (idx < N) ? deg[idx] : 0;
    s += v[k];
  }
  tsum[tid] = s;
  __syncthreads();
  for (int off = 1; off < 256; off <<= 1){
    int val = (tid >= off) ? tsum[tid - off] : 0;
    __syncthreads();
    tsum[tid] += val;
    __syncthreads();
  }
  int excl = (tid == 0) ? 0 : tsum[tid - 1];
  int b = boff[blockIdx.x] + excl;
#pragma unroll
  for (int k = 0; k < 4; k++){
    int idx = i0 + k;
    if (idx < N){
      row_start[idx] = b;
      cursor[idx]    = b;
      b += v[k];
    }
  }
}

// ---------------------------------------------------------------------------
// Edge prep: permutation scatter + raw features (written permuted) + stats
// ---------------------------------------------------------------------------
__global__ void edge_prep(const float* __restrict__ pos,
                          const int* __restrict__ snd,
                          const int* __restrict__ rcv,
                          int* __restrict__ cursor,
                          int* __restrict__ psnd,
                          int* __restrict__ prcv,
                          float* __restrict__ ef_raw,
                          float* __restrict__ epart, int E){
  __shared__ float red[4][6];
  int tid = threadIdx.x, w = tid >> 6, l = tid & 63;
  int e = blockIdx.x * blockDim.x + tid;
  float s[6] = {0.f,0.f,0.f,0.f,0.f,0.f};
  if (e < E){
    int si = snd[e], ri = rcv[e];
    int p = atomicAdd(&cursor[ri], 1);
    psnd[p] = si;
    prcv[p] = ri;
    float rx = pos[2*si]   - pos[2*ri];
    float ry = pos[2*si+1] - pos[2*ri+1];
    float nm = sqrtf(rx*rx + ry*ry);
    ef_raw[3*p]   = rx;
    ef_raw[3*p+1] = ry;
    ef_raw[3*p+2] = nm;
    s[0] = rx; s[1] = ry; s[2] = nm;
    s[3] = rx*rx; s[4] = ry*ry; s[5] = nm*nm;
  }
#pragma unroll
  for (int k = 0; k < 6; k++) s[k] = wave_sum(s[k]);
  if (l == 0)
#pragma unroll
    for (int k = 0; k < 6; k++) red[w][k] = s[k];
  __syncthreads();
  if (tid < 6)
    epart[(size_t)blockIdx.x * 6 + tid] =
      red[0][tid] + red[1][tid] + red[2][tid] + red[3][tid];
}

// ---------------------------------------------------------------------------
// Node stats partials
// ---------------------------------------------------------------------------
__global__ void node_stats(const float* __restrict__ zl,
                           const float* __restrict__ z_target,
                           float* __restrict__ npart, int N){
  __shared__ float red[4][12];
  int tid = threadIdx.x, w = tid >> 6, l = tid & 63;
  int n = blockIdx.x * blockDim.x + tid;
  float s[12];
#pragma unroll
  for (int i = 0; i < 12; i++) s[i] = 0.f;
  if (n < N){
#pragma unroll
    for (int d = 0; d < 3; d++){
      float z = zl[3*n+d];
      float t = z_target[3*n+d] - z;
      s[d]   = z;  s[3+d] = z*z;
      s[6+d] = t;  s[9+d] = t*t;
    }
  }
#pragma unroll
  for (int i = 0; i < 12; i++) s[i] = wave_sum(s[i]);
  if (l == 0)
#pragma unroll
    for (int i = 0; i < 12; i++) red[w][i] = s[i];
  __syncthreads();
  if (tid < 12)
    npart[(size_t)blockIdx.x * 12 + tid] =
      red[0][tid] + red[1][tid] + red[2][tid] + red[3][tid];
}

// ---------------------------------------------------------------------------
// Reduce partials + finalize stats.
// fin: em[0..2] es[3..5] nm[6..8] ns[9..11] om[12..14] os[15..17]
// ---------------------------------------------------------------------------
__global__ void reduce_finalize(const float* __restrict__ ep, int ne,
                                const float* __restrict__ np_, int nn,
                                float* __restrict__ fin, int E, int N){
  __shared__ float red[4];
  __shared__ float raw[18];
  int tid = threadIdx.x, w = tid >> 6, l = tid & 63;
  for (int j = 0; j < 6; j++){
    float s = 0.f;
    for (int b = tid; b < ne; b += 256) s += ep[(size_t)b * 6 + j];
    s = wave_sum(s);
    if (l == 0) red[w] = s;
    __syncthreads();
    if (tid == 0) raw[j] = red[0] + red[1] + red[2] + red[3];
    __syncthreads();
  }
  for (int j = 0; j < 12; j++){
    float s = 0.f;
    for (int b = tid; b < nn; b += 256) s += np_[(size_t)b * 12 + j];
    s = wave_sum(s);
    if (l == 0) red[w] = s;
    __syncthreads();
    if (tid == 0) raw[6 + j] = red[0] + red[1] + red[2] + red[3];
    __syncthreads();
  }
  if (tid == 0){
#pragma unroll
    for (int d = 0; d < 3; d++){
      float cE = (float)E, cN = (float)N;
      float m, v;
      m = raw[0+d] / cE; v = fmaxf(raw[3+d]/cE - m*m, 0.f);
      fin[0+d] = m;  fin[3+d]  = fmaxf(sqrtf(v), 1e-8f);
      m = raw[6+d] / cN; v = fmaxf(raw[9+d]/cN - m*m, 0.f);
      fin[6+d] = m;  fin[9+d]  = fmaxf(sqrtf(v), 1e-8f);
      m = raw[12+d] / cN; v = fmaxf(raw[15+d]/cN - m*m, 0.f);
      fin[12+d] = m; fin[15+d] = fmaxf(sqrtf(v), 1e-8f);
    }
  }
}

// ---------------------------------------------------------------------------
// Weight packing: fp32 [K][128] -> bf16 fragment-major (1KB per B-fragment)
// ---------------------------------------------------------------------------
__global__ void pack_weights(const float* __restrict__ encEW2,
                             const float* __restrict__ encNW2,
                             const float* __restrict__ decW1,
                             const float* __restrict__ beW1,
                             const float* __restrict__ beW2,
                             const float* __restrict__ bnW1,
                             const float* __restrict__ bnW2,
                             __hip_bfloat16* __restrict__ wp){
  int y = blockIdx.y;
  const float* src; __hip_bfloat16* dst; int K;
  if (y == 0){ src = encEW2; dst = wp;          K = 128; }
  else if (y == 1){ src = encNW2; dst = wp + 16384; K = 128; }
  else if (y == 2){ src = decW1;  dst = wp + 32768; K = 128; }
  else {
    int b = (y - 3) >> 2, j = (y - 3) & 3;
    __hip_bfloat16* base = wp + 49152 + b * 114688;
    if (j == 0){ src = beW1 + b*49152; dst = base;          K = 384; }
    else if (j == 1){ src = beW2 + b*16384; dst = base + 49152; K = 128; }
    else if (j == 2){ src = bnW1 + b*32768; dst = base + 65536; K = 256; }
    else { src = bnW2 + b*16384; dst = base + 98304; K = 128; }
  }
  int id = blockIdx.x * blockDim.x + threadIdx.x;
  if (id >= 128 * K) return;
  int c = id >> 12;
  int r = id & 4095;
  int t = r >> 9;
  int l = (r >> 3) & 63;
  int j = r & 7;
  int k = c * 32 + ((l >> 4) << 3) + j;
  int n = t * 16 + (l & 15);
  dst[id] = __float2bfloat16(src[k * 128 + n]);
}

// ---------------------------------------------------------------------------
// Fused encoder: out = (relu(norm(raw3)@W1+b1)) @ W2 + b2; W2 staged in LDS
// ---------------------------------------------------------------------------
__launch_bounds__(256)
__global__ void encoder_fused(const float* __restrict__ raw,
                              const float* __restrict__ mptr,
                              const float* __restrict__ sptr,
                              const float* __restrict__ W1,   // [3][128] f32
                              const float* __restrict__ b1,
                              const __hip_bfloat16* __restrict__ W2f, // frag-major
                              const float* __restrict__ b2,
                              __hip_bfloat16* __restrict__ out, int rows){
  __shared__ __align__(16) short bsh[16384];
  const int tid = threadIdx.x, w = tid >> 6, l = tid & 63, m = l & 15, q = l >> 4;
  const short* wsrc = (const short*)W2f;
#pragma unroll
  for (int i = 0; i < 8; i++){
    int inst = w * 8 + i;
    gl_lds16(wsrc + inst * 512 + l * 8, &bsh[inst * 512]);
  }
  float s0 = mptr[0], s1 = mptr[1], s2 = mptr[2];
  float d0 = sptr[0], d1 = sptr[1], d2 = sptr[2];
  const int row0 = blockIdx.x * 64 + w * 16;
  const int ra = min(row0 + m, rows - 1);
  float x0 = (raw[3*ra]   - s0) / d0;
  float x1 = (raw[3*ra+1] - s1) / d1;
  float x2 = (raw[3*ra+2] - s2) / d2;
  bf16x8 afr[4];
#pragma unroll
  for (int c = 0; c < 4; c++){
    int nb = c * 32 + q * 8;
#pragma unroll
    for (int j = 0; j < 8; j++){
      float h = b1[nb+j] + x0 * W1[nb+j] + x1 * W1[128+nb+j] + x2 * W1[256+nb+j];
      afr[c][j] = f2bf(fmaxf(h, 0.f));
    }
  }
  f32x4 acc[8];
#pragma unroll
  for (int t = 0; t < 8; t++) acc[t] = (f32x4){0.f,0.f,0.f,0.f};
  __syncthreads();
#pragma unroll
  for (int c = 0; c < 4; c++){
#pragma unroll
    for (int t = 0; t < 8; t++){
      bf16x8 b = *(const bf16x8*)&bsh[(c*8 + t)*512 + l*8];
      acc[t] = __builtin_amdgcn_mfma_f32_16x16x32_bf16(afr[c], b, acc[t], 0, 0, 0);
    }
  }
  const int row_d = row0 + q * 4;
#pragma unroll
  for (int t = 0; t < 8; t++){
    int col = t * 16 + m;
    float bb = b2[col];
#pragma unroll
    for (int r = 0; r < 4; r++){
      int e = row_d + r;
      if (e < rows) out[(size_t)e * HDIM + col] = __float2bfloat16(acc[t][r] + bb);
    }
  }
}

// ---------------------------------------------------------------------------
// Decoder layer 1: out_f32 = relu(A_bf16 @ W + b); W staged once in LDS
// ---------------------------------------------------------------------------
__launch_bounds__(256)
__global__ void gemm128_g(const __hip_bfloat16* __restrict__ A,
                          const __hip_bfloat16* __restrict__ Wf,
                          const float* __restrict__ bias,
                          float* __restrict__ out, int rows){
  __shared__ __align__(16) short bsh[16384];
  const int tid = threadIdx.x, w = tid >> 6, l = tid & 63, m = l & 15, q = l >> 4;
  const short* wsrc = (const short*)Wf;
#pragma unroll
  for (int i = 0; i < 8; i++){
    int inst = w * 8 + i;
    gl_lds16(wsrc + inst * 512 + l * 8, &bsh[inst * 512]);
  }
  const int row0 = blockIdx.x * 64 + w * 16;
  const int ra = min(row0 + m, rows - 1);
  const short* pa = (const short*)A + (size_t)ra * HDIM + q * 8;
  bf16x8 afr[4];
#pragma unroll
  for (int c = 0; c < 4; c++) afr[c] = *(const bf16x8*)(pa + c * 32);
  f32x4 acc[8];
#pragma unroll
  for (int t = 0; t < 8; t++) acc[t] = (f32x4){0.f,0.f,0.f,0.f};
  __syncthreads();
#pragma unroll
  for (int c = 0; c < 4; c++){
#pragma unroll
    for (int t = 0; t < 8; t++){
      bf16x8 b = *(const bf16x8*)&bsh[(c*8 + t)*512 + l*8];
      acc[t] = __builtin_amdgcn_mfma_f32_16x16x32_bf16(afr[c], b, acc[t], 0, 0, 0);
    }
  }
  const int row_d = row0 + q * 4;
#pragma unroll
  for (int t = 0; t < 8; t++){
    int col = t * 16 + m;
    float bb = bias[col];
#pragma unroll
    for (int r = 0; r < 4; r++){
      int e = row_d + r;
      if (e < rows) out[(size_t)e * HDIM + col] = fmaxf(acc[t][r] + bb, 0.f);
    }
  }
}

// ---------------------------------------------------------------------------
// msg_pre: u[n][0..255] = nf[n] @ [W1s | W1r]  (per message block)
// ---------------------------------------------------------------------------
__launch_bounds__(512)
__global__ void msg_pre(const __hip_bfloat16* __restrict__ nf,
                        const __hip_bfloat16* __restrict__ eWf, // full eW1 frag-major
                        __hip_bfloat16* __restrict__ u, int N){
  __shared__ __align__(16) short wsh[32768];   // 64 KB = chunks 4..11
  const int tid = threadIdx.x, w = tid >> 6, l = tid & 63, m = l & 15, q = l >> 4;
  const short* wsrc = (const short*)eWf + 4 * 4096;
#pragma unroll
  for (int i = 0; i < 8; i++){
    int inst = w * 8 + i;
    gl_lds16(wsrc + inst * 512 + l * 8, &wsh[inst * 512]);
  }
  const int row0 = blockIdx.x * 128 + w * 16;
  const int ra = min(row0 + m, N - 1);
  const short* pa = (const short*)nf + (size_t)ra * HDIM + q * 8;
  bf16x8 afr[4];
#pragma unroll
  for (int c = 0; c < 4; c++) afr[c] = *(const bf16x8*)(pa + c * 32);
  f32x4 acc[16];
#pragma unroll
  for (int t = 0; t < 16; t++) acc[t] = (f32x4){0.f,0.f,0.f,0.f};
  __syncthreads();
#pragma unroll
  for (int c = 0; c < 4; c++){
#pragma unroll
    for (int t = 0; t < 16; t++){
      int cc = (t < 8) ? c : (4 + c);
      bf16x8 b = *(const bf16x8*)&wsh[cc * 4096 + (t & 7) * 512 + l * 8];
      acc[t] = __builtin_amdgcn_mfma_f32_16x16x32_bf16(afr[c], b, acc[t], 0, 0, 0);
    }
  }
  const int row_d = row0 + q * 4;
#pragma unroll
  for (int t = 0; t < 16; t++){
    int col = t * 16 + m;
#pragma unroll
    for (int r = 0; r < 4; r++){
      int n = row_d + r;
      if (n < N) u[(size_t)n * 256 + col] = __float2bfloat16(acc[t][r]);
    }
  }
}

// ---------------------------------------------------------------------------
// Edge block (R13): ef += W2*relu(ef@W1e + u_s[s]+u_r[r]+b1)+b2
// ---------------------------------------------------------------------------
__launch_bounds__(512)
__global__ void edge_block(const int* __restrict__ psnd,
                           const int* __restrict__ prcv,
                           const __hip_bfloat16* __restrict__ u,   // [n][256] bf16
                           __hip_bfloat16* __restrict__ ef,
                           const __hip_bfloat16* __restrict__ Wfrag, // eW1|eW2 frag-major
                           const float* __restrict__ b1,
                           const float* __restrict__ b2,
                           int E){
  __shared__ __align__(16) short bsh[2][4096];
  __shared__ __align__(16) short hsh[8][16][136];
  const int tid = threadIdx.x, w = tid >> 6, l = tid & 63, m = l & 15, q = l >> 4;
  const short* wsrc = (const short*)Wfrag;
  gl_lds16(wsrc + w*512 + l*8, &bsh[0][w*512]);

  const int row0 = blockIdx.x * 128 + w * 16;
  const int ra = min(row0 + m, E - 1);
  const short* pe = (const short*)ef + (size_t)ra * HDIM + q * 8;
  bf16x8 afr[4];
#pragma unroll
  for (int c = 0; c < 4; c++) afr[c] = *(const bf16x8*)(pe + c * 32);

  {
    int grow = min(row0 + (l >> 2), E - 1);
    int us_row = psnd[grow], ur_row = prcv[grow];
    const short* pus = (const short*)u + (size_t)us_row * 256 + (l & 3) * 32;
    const short* pur = (const short*)u + (size_t)ur_row * 256 + 128 + (l & 3) * 32;
    short* hdst = &hsh[w][l >> 2][(l & 3) * 32];
#pragma unroll
    for (int k = 0; k < 4; k++){
      bf16x8 a = *(const bf16x8*)(pus + k * 8);
      bf16x8 b = *(const bf16x8*)(pur + k * 8);
      bf16x8 s;
#pragma unroll
      for (int j = 0; j < 8; j++) s[j] = f2bf(bfb2f(a[j]) + bfb2f(b[j]));
      *(bf16x8*)(hdst + k * 8) = s;
    }
  }
  const int orow = row0 + (l >> 2);
  const int orc = min(orow, E - 1);
  const short* pold = (const short*)ef + (size_t)orc * HDIM + (l & 3) * 32;
  bf16x8 vold[4];
#pragma unroll
  for (int k = 0; k < 4; k++) vold[k] = *(const bf16x8*)(pold + k * 8);

  f32x4 acc[8];
#pragma unroll
  for (int t = 0; t < 8; t++) acc[t] = (f32x4){0.f,0.f,0.f,0.f};
  __syncthreads();
#pragma unroll
  for (int c = 0; c < 4; c++){
    if (c + 1 < 4)
      gl_lds16(wsrc + (c+1)*4096 + w*512 + l*8, &bsh[(c+1)&1][w*512]);
    const short* bb = &bsh[c & 1][0];
#pragma unroll
    for (int t = 0; t < 8; t++){
      bf16x8 b = *(const bf16x8*)(bb + t*512 + l*8);
      acc[t] = __builtin_amdgcn_mfma_f32_16x16x32_bf16(afr[c], b, acc[t], 0, 0, 0);
    }
    if (c + 1 < 4) __syncthreads();
  }
#pragma unroll
  for (int t = 0; t < 8; t++){
    float bb = b1[t * 16 + m];
#pragma unroll
    for (int r = 0; r < 4; r++){
      float uval = bfb2f(hsh[w][q*4 + r][t*16 + m]);
      hsh[w][q*4 + r][t*16 + m] = f2bf(fmaxf(acc[t][r] + uval + bb, 0.f));
    }
  }
  const short* ph = &hsh[w][m][0] + q * 8;
  const short* w2 = wsrc + 49152;
  f32x4 acc2[8];
#pragma unroll
  for (int t = 0; t < 8; t++) acc2[t] = (f32x4){0.f,0.f,0.f,0.f};
#pragma unroll
  for (int c = 0; c < 4; c++){
    bf16x8 a = *(const bf16x8*)(ph + c * 32);
#pragma unroll
    for (int t = 0; t < 8; t++){
      bf16x8 b = *(const bf16x8*)(w2 + ((c*8 + t)*64 + l)*8);
      acc2[t] = __builtin_amdgcn_mfma_f32_16x16x32_bf16(a, b, acc2[t], 0, 0, 0);
    }
  }
#pragma unroll
  for (int t = 0; t < 8; t++){
    float bb = b2[t * 16 + m];
#pragma unroll
    for (int r = 0; r < 4; r++)
      hsh[w][q*4 + r][t*16 + m] = f2bf(acc2[t][r] + bb);
  }
  if (orow < E){
    const short* src = &hsh[w][l >> 2][(l & 3) * 32];
    short* dst = (short*)ef + (size_t)orow * HDIM + (l & 3) * 32;
#pragma unroll
    for (int k = 0; k < 4; k++){
      bf16x8 vnew = *(const bf16x8*)(src + k * 8);
      bf16x8 vo;
#pragma unroll
      for (int j = 0; j < 8; j++) vo[j] = f2bf(bfb2f(vnew[j]) + bfb2f(vold[k][j]));
      *(bf16x8*)(dst + k * 8) = vo;
    }
  }
}

// ---------------------------------------------------------------------------
// Node block (R13): agg = streaming CSR gather; nf += MLP([nf|agg])
// W1 = 8 chunks staged, W2 from global.
// ---------------------------------------------------------------------------
__launch_bounds__(512)
__global__ void node_block(const int* __restrict__ row_start,
                           const __hip_bfloat16* __restrict__ ef,  // permuted
                           __hip_bfloat16* __restrict__ nf,
                           const __hip_bfloat16* __restrict__ Wfrag, // nW1|nW2
                           const float* __restrict__ b1,
                           const float* __restrict__ b2,
                           int N){
  __shared__ __align__(16) short bsh[2][4096];
  __shared__ __align__(16) short hsh[8][16][136];
  const int tid = threadIdx.x, w = tid >> 6, l = tid & 63, m = l & 15, q = l >> 4;
  const short* wsrc = (const short*)Wfrag;
  gl_lds16(wsrc + w*512 + l*8, &bsh[0][w*512]);

  const int row0 = blockIdx.x * 128 + w * 16;
  const int ra = min(row0 + m, N - 1);
  const short* pn = (const short*)nf + (size_t)ra * HDIM + q * 8;
  bf16x8 afr[8];
#pragma unroll
  for (int c = 0; c < 4; c++) afr[c] = *(const bf16x8*)(pn + c * 32);
  const int orow = row0 + (l >> 2);
  const int orc = min(orow, N - 1);
  const short* pold = (const short*)nf + (size_t)orc * HDIM + (l & 3) * 32;
  bf16x8 vold[4];
#pragma unroll
  for (int k = 0; k < 4; k++) vold[k] = *(const bf16x8*)(pold + k * 8);

  float sum[4][8];
#pragma unroll
  for (int c = 0; c < 4; c++)
#pragma unroll
    for (int j = 0; j < 8; j++) sum[c][j] = 0.f;
  int s0 = row_start[ra], s1 = row_start[ra + 1];
  for (int it = s0; it < s1; it++){
    const short* pf = (const short*)ef + (size_t)it * HDIM + q * 8;
#pragma unroll
    for (int c = 0; c < 4; c++){
      bf16x8 v = *(const bf16x8*)(pf + c * 32);
#pragma unroll
      for (int j = 0; j < 8; j++) sum[c][j] += bfb2f(v[j]);
    }
  }
#pragma unroll
  for (int c = 0; c < 4; c++)
#pragma unroll
    for (int j = 0; j < 8; j++) afr[4 + c][j] = f2bf(sum[c][j]);

  f32x4 acc[8];
#pragma unroll
  for (int t = 0; t < 8; t++) acc[t] = (f32x4){0.f,0.f,0.f,0.f};
  __syncthreads();
#pragma unroll
  for (int c = 0; c < 8; c++){
    if (c + 1 < 8)
      gl_lds16(wsrc + (c+1)*4096 + w*512 + l*8, &bsh[(c+1)&1][w*512]);
    const short* bb = &bsh[c & 1][0];
#pragma unroll
    for (int t = 0; t < 8; t++){
      bf16x8 b = *(const bf16x8*)(bb + t*512 + l*8);
      acc[t] = __builtin_amdgcn_mfma_f32_16x16x32_bf16(afr[c], b, acc[t], 0, 0, 0);
    }
    if (c + 1 < 8) __syncthreads();
  }
#pragma unroll
  for (int t = 0; t < 8; t++){
    float bb = b1[t * 16 + m];
#pragma unroll
    for (int r = 0; r < 4; r++)
      hsh[w][q*4 + r][t*16 + m] = f2bf(fmaxf(acc[t][r] + bb, 0.f));
  }
  const short* ph = &hsh[w][m][0] + q * 8;
  const short* w2 = wsrc + 32768;
  f32x4 acc2[8];
#pragma unroll
  for (int t = 0; t < 8; t++) acc2[t] = (f32x4){0.f,0.f,0.f,0.f};
#pragma unroll
  for (int c = 0; c < 4; c++){
    bf16x8 a = *(const bf16x8*)(ph + c * 32);
#pragma unroll
    for (int t = 0; t < 8; t++){
      bf16x8 b = *(const bf16x8*)(w2 + ((c*8 + t)*64 + l)*8);
      acc2[t] = __builtin_amdgcn_mfma_f32_16x16x32_bf16(a, b, acc2[t], 0, 0, 0);
    }
  }
#pragma unroll
  for (int t = 0; t < 8; t++){
    float bb = b2[t * 16 + m];
#pragma unroll
    for (int r = 0; r < 4; r++)
      hsh[w][q*4 + r][t*16 + m] = f2bf(acc2[t][r] + bb);
  }
  if (orow < N){
    const short* src = &hsh[w][l >> 2][(l & 3) * 32];
    short* dst = (short*)nf + (size_t)orow * HDIM + (l & 3) * 32;
#pragma unroll
    for (int k = 0; k < 4; k++){
      bf16x8 vnew = *(const bf16x8*)(src + k * 8);
      bf16x8 vo;
#pragma unroll
      for (int j = 0; j < 8; j++) vo[j] = f2bf(bfb2f(vnew[j]) + bfb2f(vold[k][j]));
      *(bf16x8*)(dst + k * 8) = vo;
    }
  }
}

// ---------------------------------------------------------------------------
// Decoder final layer: [rows,128] fp32 @ [128,3] + b
// ---------------------------------------------------------------------------
__global__ void dec_final(const float* __restrict__ hbuf,
                          const float* __restrict__ W2,
                          const float* __restrict__ b2,
                          float* __restrict__ outd, int rows){
  __shared__ float hl[64 * 129];
  __shared__ float Wl[HDIM * 3];
  __shared__ float bl[3];
  int t = threadIdx.x;
  int node0 = blockIdx.x * 64;
  for (int i = t; i < HDIM * 3; i += 256) Wl[i] = W2[i];
  if (t < 3) bl[t] = b2[t];
#pragma unroll
  for (int i = 0; i < 32; i++){
    int lin = t + i * 256;
    int r = lin >> 7;
    int c = lin & 127;
    int node = node0 + r;
    hl[r * 129 + c] = (node < rows) ? hbuf[(size_t)node * HDIM + c] : 0.f;
  }
  __syncthreads();
  if (t < 64){
    int node = node0 + t;
    if (node < rows){
      float a0 = bl[0], a1 = bl[1], a2 = bl[2];
      for (int k = 0; k < HDIM; k++){
        float v = hl[t * 129 + k];
        a0 += v * Wl[k * 3];
        a1 += v * Wl[k * 3 + 1];
        a2 += v * Wl[k * 3 + 2];
      }
      outd[3 * node]     = a0;
      outd[3 * node + 1] = a1;
      outd[3 * node + 2] = a2;
    }
  }
}

// ---------------------------------------------------------------------------
// Epilogue + finalize (partials, no atomics)
// ---------------------------------------------------------------------------
__global__ void epilogue(const float* __restrict__ dec_out,
                         const float* __restrict__ zl,
                         const float* __restrict__ z_target,
                         const float* __restrict__ fin,
                         float* __restrict__ d_out,
                         float* __restrict__ lpart, int N){
  __shared__ float red[4][4];
  int tid = threadIdx.x, w = tid >> 6, l = tid & 63;
  int n = blockIdx.x * blockDim.x + tid;
  float s[4] = {0.f,0.f,0.f,0.f};
  if (n < N){
#pragma unroll
    for (int d = 0; d < 3; d++){
      float om = fin[12 + d], os = fin[15 + d];
      float o   = dec_out[3*n + d];
      float zld = zl[3*n + d];
      float zt  = z_target[3*n + d];
      float tgt = zt - zld;
      float tn  = (tgt - om) / os;
      float diff = tn - o;
      s[0] += diff * diff;
      float zp = zld + o * os + om;
      d_out[3*n + d] = zp;
      float e = zp - zt;
      s[1 + d] = e * e;
    }
  }
#pragma unroll
  for (int k = 0; k < 4; k++) s[k] = wave_sum(s[k]);
  if (l == 0)
#pragma unroll
    for (int k = 0; k < 4; k++) red[w][k] = s[k];
  __syncthreads();
  if (tid < 4)
    lpart[(size_t)blockIdx.x * 4 + tid] =
      red[0][tid] + red[1][tid] + red[2][tid] + red[3][tid];
}

__global__ void finalize_out(const float* __restrict__ lpart, int nb,
                             float* __restrict__ d_out, int N){
  __shared__ float red[4];
  __shared__ float vals[4];
  int tid = threadIdx.x, w = tid >> 6, l = tid & 63;
  for (int j = 0; j < 4; j++){
    float s = 0.f;
    for (int b = tid; b < nb; b += 256) s += lpart[(size_t)b * 4 + j];
    s = wave_sum(s);
    if (l == 0) red[w] = s;
    __syncthreads();
    if (tid == 0) vals[j] = red[0] + red[1] + red[2] + red[3];
    __syncthreads();
  }
  if (tid == 0){
    float cN = (float)N;
    float loss = vals[0] / (3.f * cN);
    float rmse = (sqrtf(vals[1] / cN) + sqrtf(vals[2] / cN) + sqrtf(vals[3] / cN)) / 3.f;
    d_out[(size_t)3 * N]     = loss;
    d_out[(size_t)3 * N + 1] = rmse;
  }
}

// ---------------------------------------------------------------------------
extern "C" void kernel_launch(void* const* d_in, const int* in_sizes, int n_in,
                              void* d_out, int out_size, void* d_ws, size_t ws_size,
                              hipStream_t stream){
  const float* z           = (const float*)d_in[0];
  const float* z_target    = (const float*)d_in[1];
  const float* pos         = (const float*)d_in[2];
  const float* enc_node_W1 = (const float*)d_in[3];
  const float* enc_node_b1 = (const float*)d_in[4];
  const float* enc_node_W2 = (const float*)d_in[5];
  const float* enc_node_b2 = (const float*)d_in[6];
  const float* enc_edge_W1 = (const float*)d_in[7];
  const float* enc_edge_b1 = (const float*)d_in[8];
  const float* enc_edge_W2 = (const float*)d_in[9];
  const float* enc_edge_b2 = (const float*)d_in[10];
  const float* dec_W1      = (const float*)d_in[11];
  const float* dec_b1      = (const float*)d_in[12];
  const float* dec_W2      = (const float*)d_in[13];
  const float* dec_b2      = (const float*)d_in[14];
  const float* blk_edge_W1 = (const float*)d_in[15];
  const float* blk_edge_b1 = (const float*)d_in[16];
  const float* blk_edge_W2 = (const float*)d_in[17];
  const float* blk_edge_b2 = (const float*)d_in[18];
  const float* blk_node_W1 = (const float*)d_in[19];
  const float* blk_node_b1 = (const float*)d_in[20];
  const float* blk_node_W2 = (const float*)d_in[21];
  const float* blk_node_b2 = (const float*)d_in[22];
  const int*   senders     = (const int*)d_in[23];
  const int*   receivers   = (const int*)d_in[24];

  const int N = in_sizes[1] / 3;
  const int E = in_sizes[23];
  const float* zl = z + (size_t)N * 3;

  const int neb = ceil_div(E, TPB);
  const int nnb = ceil_div(N, TPB);
  const int nsb = ceil_div(N, 1024);   // scan blocks

  char* p = (char*)d_ws;
  auto carve = [&](size_t bytes) -> char* {
    char* r = p; p += (bytes + 255) & ~(size_t)255; return r;
  };
  float* stats_fin = (float*)carve(32 * 4);
  float* epart     = (float*)carve((size_t)neb * 6 * 4);
  float* npart     = (float*)carve((size_t)nnb * 12 * 4);
  float* lpart     = (float*)carve((size_t)nnb * 4 * 4);
  float* ef_raw    = (float*)carve((size_t)E * 3 * 4);
  float* dec_out   = (float*)carve((size_t)N * 3 * 4);
  float* hbuf      = (float*)carve((size_t)N * HDIM * 4);
  int*   deg       = (int*)carve((size_t)N * 4);
  int*   bsum      = (int*)carve((size_t)(nsb + 1) * 4);
  int*   boff      = (int*)carve((size_t)(nsb + 1) * 4);
  int*   row_start = (int*)carve((size_t)(N + 1) * 4);
  int*   cursor    = (int*)carve((size_t)N * 4);
  int*   psnd      = (int*)carve((size_t)E * 4);
  int*   prcv      = (int*)carve((size_t)E * 4);
  __hip_bfloat16* wp = (__hip_bfloat16*)carve((size_t)507904 * 2);
  __hip_bfloat16* ef = (__hip_bfloat16*)carve((size_t)E * HDIM * 2);
  __hip_bfloat16* nf = (__hip_bfloat16*)carve((size_t)N * HDIM * 2);
  __hip_bfloat16* u  = (__hip_bfloat16*)carve((size_t)N * 256 * 2);

  float* out = (float*)d_out;

  hipMemsetAsync(deg, 0, (size_t)N * 4, stream);

  csr_hist<<<neb, TPB, 0, stream>>>(receivers, deg, E);
  scan_pass1<<<nsb, TPB, 0, stream>>>(deg, bsum, N);
  scan_pass2<<<1, 64, 0, stream>>>(bsum, boff, nsb, row_start, N, E);
  scan_pass3<<<nsb, TPB, 0, stream>>>(deg, boff, row_start, cursor, N);
  edge_prep<<<neb, TPB, 0, stream>>>(pos, senders, receivers, cursor,
                                     psnd, prcv, ef_raw, epart, E);

  node_stats<<<nnb, TPB, 0, stream>>>(zl, z_target, npart, N);
  reduce_finalize<<<1, TPB, 0, stream>>>(epart, neb, npart, nnb, stats_fin, E, N);

  pack_weights<<<dim3(192, 19), TPB, 0, stream>>>(enc_edge_W2, enc_node_W2, dec_W1,
                                                  blk_edge_W1, blk_edge_W2,
                                                  blk_node_W1, blk_node_W2, wp);

  encoder_fused<<<ceil_div(E, 64), TPB, 0, stream>>>(ef_raw, stats_fin + 0, stats_fin + 3,
                                                     enc_edge_W1, enc_edge_b1,
                                                     wp, enc_edge_b2, ef, E);
  encoder_fused<<<ceil_div(N, 64), TPB, 0, stream>>>(zl, stats_fin + 6, stats_fin + 9,
                                                     enc_node_W1, enc_node_b1,
                                                     wp + 16384, enc_node_b2, nf, N);

  for (int b = 0; b < 4; b++){
    const __hip_bfloat16* eWf = wp + 49152 + (size_t)b * 114688;   // eW1|eW2
    const __hip_bfloat16* nWf = eWf + 65536;                       // nW1|nW2
    const float* eb1 = blk_edge_b1 + (size_t)b * 128;
    const float* eb2 = blk_edge_b2 + (size_t)b * 128;
    const float* nb1 = blk_node_b1 + (size_t)b * 128;
    const float* nb2 = blk_node_b2 + (size_t)b * 128;

    msg_pre<<<ceil_div(N, 128), 512, 0, stream>>>(nf, eWf, u, N);
    edge_block<<<ceil_div(E, 128), 512, 0, stream>>>(psnd, prcv, u, ef,
                                                     eWf, eb1, eb2, E);
    node_block<<<ceil_div(N, 128), 512, 0, stream>>>(row_start, ef, nf,
                                                     nWf, nb1, nb2, N);
  }

  gemm128_g<<<ceil_div(N, 64), TPB, 0, stream>>>(nf, wp + 32768, dec_b1, hbuf, N);
  dec_final<<<ceil_div(N, 64), TPB, 0, stream>>>(hbuf, dec_W2, dec_b2, dec_out, N);

  epilogue<<<nnb, TPB, 0, stream>>>(dec_out, zl, z_target, stats_fin,
                                    out, lpart, N);
  finalize_out<<<1, TPB, 0, stream>>>(lpart, nnb, out, N);
}